// Round 2
// baseline (190.873 us; speedup 1.0000x reference)
//
#include <hip/hip_runtime.h>
#include <math.h>

#define N_NODE    1000000
#define N_BOND    100000
#define K_TWIST   40
#define MAX_ORDER 8
#define N_DOMAIN  10000
#define N_PER_DOM 100           // N_NODE / N_DOMAIN
#define N_GROUP   12500         // N_BOND / MAX_ORDER
#define N_TWIST   500000        // N_GROUP * K_TWIST  (nodes >= N_TWIST never twisted)
#define SIGMA_MAXF 3.14159265358979323846f

#define CBLK  512
#define CGRID ((N_GROUP + CBLK - 1) / CBLK)   // 25 blocks -> trivially co-resident

// Scratch layout:
//   ws: rt table, 10000*12 floats = 480,000 B (proven-safe footprint)
//   out-high (floats [1.5M,3M)): M0 | M1 | sums | barrier ctrs (32 B)
//   - all consumed before apply_high overwrites that region.
// R5 lesson (this session): a spin loop polling with __ATOMIC_ACQUIRE emits
// buffer_inv (L1+L2 invalidate) EVERY iteration -> 25 spinning blocks thrash
// all 8 XCD L2s -> every Mp gather goes to HBM at ~900cy with ~200 waves of
// parallelism -> ~7 us/barrier. Fix: RELAXED polls (sc1 read from coherent
// point, no invalidate) + ONE full __threadfence() after spin exit. The single
// post-spin invalidate is required (stale Mp lines from prior orders) and
// sufficient (post-release-flush L2 refills are fresh).
// ---------------------------------------------------------------------------
__device__ __forceinline__ void grid_barrier(unsigned int* ctr, int phase,
                                             unsigned int nblk)
{
    __syncthreads();
    if (threadIdx.x == 0) {
        __threadfence();  // release: flush M writes to device-visible point
        __hip_atomic_fetch_add(&ctr[phase], 1u, __ATOMIC_RELEASE,
                               __HIP_MEMORY_SCOPE_AGENT);
        long guard = 0;
        while (__hip_atomic_load(&ctr[phase], __ATOMIC_RELAXED,
                                 __HIP_MEMORY_SCOPE_AGENT) < nblk) {
            __builtin_amdgcn_s_sleep(1);
            if (++guard > (1L << 27)) break;   // hang guard; wrong results
        }                                      // beat a hung bench
        __threadfence();  // acquire: ONE invalidate of stale cached M lines
    }
    __syncthreads();
}

// ---------------------------------------------------------------------------
// compose_all_k: ALL 8 orders in one kernel. One thread per group.
// Order-invariant per-bond data (anno, angle, cos/sin, base endpoint
// positions) hoisted ahead of the order loop so the 16 gathers pipeline.
// Per order: read prev-order cumulative affines (own + endpoint groups),
// compose Rodrigues rotation, write current. Barrier between orders.
// Math identical to the R4-verified 8-dispatch version (absmax 0.5).
// ---------------------------------------------------------------------------
__global__ __launch_bounds__(CBLK) void compose_all_k(
    const float* __restrict__ pos, const float* __restrict__ info_level,
    const int* __restrict__ anno, const float* __restrict__ eps,
    const float* __restrict__ uni, const int* __restrict__ from_prior_p,
    float* __restrict__ M0, float* __restrict__ M1,
    unsigned int* __restrict__ ctr)
{
    int g = blockIdx.x * CBLK + threadIdx.x;
    bool active = (g < N_GROUP);

    int   ord8[MAX_ORDER], u8[MAX_ORDER], v8[MAX_ORDER];
    float c8[MAX_ORDER], s8[MAX_ORDER];
    float pux[MAX_ORDER], puy[MAX_ORDER], puz[MAX_ORDER];
    float pvx[MAX_ORDER], pvy[MAX_ORDER], pvz[MAX_ORDER];

    if (active) {
        int fp = from_prior_p[0];
        #pragma unroll
        for (int o = 0; o < MAX_ORDER; o++) {
            int b = g * MAX_ORDER + o;
            ord8[o] = anno[3*b];
            u8[o]   = anno[3*b + 1];
            v8[o]   = anno[3*b + 2];
            float info = info_level[b];
            float ang  = eps[b] * (1.0f - info) * SIGMA_MAXF;
            if (fp != 0 && info == 0.0f) ang = uni[b];
            c8[o] = cosf(ang);
            s8[o] = sinf(ang);
        }
        #pragma unroll
        for (int o = 0; o < MAX_ORDER; o++) {
            int u = u8[o], v = v8[o];
            pux[o] = pos[3*u+0]; puy[o] = pos[3*u+1]; puz[o] = pos[3*u+2];
            pvx[o] = pos[3*v+0]; pvy[o] = pos[3*v+1]; pvz[o] = pos[3*v+2];
        }
    }

    #pragma unroll
    for (int o = 0; o < MAX_ORDER; o++) {
        const float* Mp = (o & 1) ? M0 : M1;
        float*       Mc = (o & 1) ? M1 : M0;
        if (active) {
            float* mg = Mc + 12 * g;
            if (ord8[o] != o) {                       // safety fallback
                if (o == 0) {
                    mg[0]=1.f; mg[1]=0.f; mg[2]=0.f;
                    mg[3]=0.f; mg[4]=1.f; mg[5]=0.f;
                    mg[6]=0.f; mg[7]=0.f; mg[8]=1.f;
                    mg[9]=0.f; mg[10]=0.f; mg[11]=0.f;
                } else {
                    const float* mp = Mp + 12 * g;
                    #pragma unroll
                    for (int k = 0; k < 12; k++) mg[k] = mp[k];
                }
            } else {
                float pu0 = pux[o], pu1 = puy[o], pu2 = puz[o];
                float pv0 = pvx[o], pv1 = pvy[o], pv2 = pvz[o];
                if (o > 0) {
                    int u = u8[o], v = v8[o];
                    if (u < N_TWIST) {
                        const float* m = Mp + 12 * (u / K_TWIST);
                        float a = m[0]*pu0 + m[1]*pu1 + m[2]*pu2 + m[9];
                        float c = m[3]*pu0 + m[4]*pu1 + m[5]*pu2 + m[10];
                        float e = m[6]*pu0 + m[7]*pu1 + m[8]*pu2 + m[11];
                        pu0 = a; pu1 = c; pu2 = e;
                    }
                    if (v < N_TWIST) {
                        const float* m = Mp + 12 * (v / K_TWIST);
                        float a = m[0]*pv0 + m[1]*pv1 + m[2]*pv2 + m[9];
                        float c = m[3]*pv0 + m[4]*pv1 + m[5]*pv2 + m[10];
                        float e = m[6]*pv0 + m[7]*pv1 + m[8]*pv2 + m[11];
                        pv0 = a; pv1 = c; pv2 = e;
                    }
                }
                float ax = pv0-pu0, ay = pv1-pu1, az = pv2-pu2;
                float inv = 1.0f / (sqrtf(ax*ax + ay*ay + az*az) + 1e-12f);
                ax *= inv; ay *= inv; az *= inv;
                float c = c8[o], s = s8[o], t = 1.0f - c;
                float R00 = c + t*ax*ax,     R01 = -s*az + t*ax*ay, R02 =  s*ay + t*ax*az;
                float R10 =  s*az + t*ay*ax, R11 = c + t*ay*ay,     R12 = -s*ax + t*ay*az;
                float R20 = -s*ay + t*az*ax, R21 =  s*ax + t*az*ay, R22 = c + t*az*az;
                if (o == 0) {
                    mg[0]=R00; mg[1]=R01; mg[2]=R02;
                    mg[3]=R10; mg[4]=R11; mg[5]=R12;
                    mg[6]=R20; mg[7]=R21; mg[8]=R22;
                    mg[9]  = pv0 - (R00*pv0 + R01*pv1 + R02*pv2);
                    mg[10] = pv1 - (R10*pv0 + R11*pv1 + R12*pv2);
                    mg[11] = pv2 - (R20*pv0 + R21*pv1 + R22*pv2);
                } else {
                    const float* mp = Mp + 12 * g;
                    mg[0] = R00*mp[0] + R01*mp[3] + R02*mp[6];
                    mg[1] = R00*mp[1] + R01*mp[4] + R02*mp[7];
                    mg[2] = R00*mp[2] + R01*mp[5] + R02*mp[8];
                    mg[3] = R10*mp[0] + R11*mp[3] + R12*mp[6];
                    mg[4] = R10*mp[1] + R11*mp[4] + R12*mp[7];
                    mg[5] = R10*mp[2] + R11*mp[5] + R12*mp[8];
                    mg[6] = R20*mp[0] + R21*mp[3] + R22*mp[6];
                    mg[7] = R20*mp[1] + R21*mp[4] + R22*mp[7];
                    mg[8] = R20*mp[2] + R21*mp[5] + R22*mp[8];
                    float d0 = mp[9]-pv0, d1 = mp[10]-pv1, d2 = mp[11]-pv2;
                    mg[9]  = R00*d0 + R01*d1 + R02*d2 + pv0;
                    mg[10] = R10*d0 + R11*d1 + R12*d2 + pv1;
                    mg[11] = R20*d0 + R21*d1 + R22*d2 + pv2;
                }
            }
        }
        if (o < MAX_ORDER - 1) grid_barrier(ctr, o, gridDim.x);
    }
}

// ---------------------------------------------------------------------------
// reduce_k: wave per domain; P = Mf * pos computed on the fly; 15 sums via
// shuffle; lane 0 stores to sums[d*15..]. All lanes useful.
// ---------------------------------------------------------------------------
__global__ __launch_bounds__(256) void reduce_k(const float* __restrict__ pos,
                                                const float* __restrict__ Mf,
                                                float* __restrict__ sums)
{
    int wave = threadIdx.x >> 6;
    int lane = threadIdx.x & 63;
    int d = blockIdx.x * 4 + wave;          // grid = 2500 -> d in [0,10000)
    float a[15];
    #pragma unroll
    for (int k = 0; k < 15; k++) a[k] = 0.f;
    for (int i = lane; i < N_PER_DOM; i += 64) {
        int n = d * N_PER_DOM + i;
        float q0 = pos[3*n+0], q1 = pos[3*n+1], q2 = pos[3*n+2];
        float p0 = q0, p1 = q1, p2 = q2;
        if (n < N_TWIST) {
            const float* m = Mf + 12 * (n / K_TWIST);
            p0 = m[0]*q0 + m[1]*q1 + m[2]*q2 + m[9];
            p1 = m[3]*q0 + m[4]*q1 + m[5]*q2 + m[10];
            p2 = m[6]*q0 + m[7]*q1 + m[8]*q2 + m[11];
        }
        a[0]+=p0;    a[1]+=p1;    a[2]+=p2;
        a[3]+=q0;    a[4]+=q1;    a[5]+=q2;
        a[6]+=p0*q0; a[7]+=p0*q1; a[8]+=p0*q2;
        a[9]+=p1*q0; a[10]+=p1*q1;a[11]+=p1*q2;
        a[12]+=p2*q0;a[13]+=p2*q1;a[14]+=p2*q2;
    }
    #pragma unroll
    for (int off = 32; off > 0; off >>= 1)
        #pragma unroll
        for (int k = 0; k < 15; k++) a[k] += __shfl_down(a[k], off);
    if (lane == 0) {
        float* sd = sums + (size_t)d * 15;
        #pragma unroll
        for (int k = 0; k < 15; k++) sd[k] = a[k];
    }
}

// ---------------------------------------------------------------------------
// 3x3 SVD-based Kabsch from 15 sums (double Jacobi on H^T H) — numerics
// identical to the R1/R3/R4-verified version.
// ---------------------------------------------------------------------------
__device__ inline void cross3d(const double a[3], const double b[3], double r[3])
{
    r[0] = a[1]*b[2] - a[2]*b[1];
    r[1] = a[2]*b[0] - a[0]*b[2];
    r[2] = a[0]*b[1] - a[1]*b[0];
}

__device__ void kabsch_from_sums(const float* s, float* __restrict__ rt)
{
    const double inv_n = 1.0 / (double)N_PER_DOM;
    double sP[3] = { s[0], s[1], s[2] };
    double sQ[3] = { s[3], s[4], s[5] };
    double H[3][3];
    #pragma unroll
    for (int i = 0; i < 3; i++)
        #pragma unroll
        for (int j = 0; j < 3; j++)
            H[i][j] = (double)s[6 + 3*i + j] - sP[i]*sQ[j]*inv_n;
    double A[3][3];
    #pragma unroll
    for (int i = 0; i < 3; i++)
        #pragma unroll
        for (int j = 0; j < 3; j++)
            A[i][j] = H[0][i]*H[0][j] + H[1][i]*H[1][j] + H[2][i]*H[2][j];
    double V[3][3] = {{1,0,0},{0,1,0},{0,0,1}};
    for (int sweep = 0; sweep < 30; sweep++) {
        double off = A[0][1]*A[0][1] + A[0][2]*A[0][2] + A[1][2]*A[1][2];
        double n2  = A[0][0]*A[0][0] + A[1][1]*A[1][1] + A[2][2]*A[2][2];
        if (off <= 1e-28 * n2) break;
        for (int pp = 0; pp < 3; pp++) {
            int p = (pp == 2) ? 1 : 0;
            int q = (pp == 0) ? 1 : 2;
            double apq = A[p][q];
            if (apq == 0.0) continue;
            double tau = (A[q][q] - A[p][p]) / (2.0 * apq);
            double tj  = (tau >= 0.0 ? 1.0 : -1.0) / (fabs(tau) + sqrt(1.0 + tau*tau));
            double cj  = 1.0 / sqrt(1.0 + tj*tj);
            double sj  = tj * cj;
            int r = 3 - p - q;
            double app = A[p][p], aqq = A[q][q];
            A[p][p] = app - tj*apq;
            A[q][q] = aqq + tj*apq;
            A[p][q] = 0.0; A[q][p] = 0.0;
            double arp = A[r][p], arq = A[r][q];
            A[r][p] = cj*arp - sj*arq; A[p][r] = A[r][p];
            A[r][q] = sj*arp + cj*arq; A[q][r] = A[r][q];
            #pragma unroll
            for (int k = 0; k < 3; k++) {
                double vp = V[k][p], vq = V[k][q];
                V[k][p] = cj*vp - sj*vq;
                V[k][q] = sj*vp + cj*vq;
            }
        }
    }
    double wv[3] = { A[0][0], A[1][1], A[2][2] };
    int i0 = 0, i1 = 1, i2 = 2;
    if (wv[i0] < wv[i1]) { int t = i0; i0 = i1; i1 = t; }
    if (wv[i0] < wv[i2]) { int t = i0; i0 = i2; i2 = t; }
    if (wv[i1] < wv[i2]) { int t = i1; i1 = i2; i2 = t; }
    double v0[3] = { V[0][i0], V[1][i0], V[2][i0] };
    double v1[3] = { V[0][i1], V[1][i1], V[2][i1] };
    double v2[3] = { V[0][i2], V[1][i2], V[2][i2] };
    double s0 = sqrt(fmax(wv[i0], 0.0));
    double Rg[3][3];
    if (s0 < 1e-200) {
        Rg[0][0]=1; Rg[0][1]=0; Rg[0][2]=0;
        Rg[1][0]=0; Rg[1][1]=1; Rg[1][2]=0;
        Rg[2][0]=0; Rg[2][1]=0; Rg[2][2]=1;
    } else {
        double u0[3], u1[3], u2[3];
        #pragma unroll
        for (int i = 0; i < 3; i++)
            u0[i] = H[i][0]*v0[0] + H[i][1]*v0[1] + H[i][2]*v0[2];
        double n0 = sqrt(u0[0]*u0[0] + u0[1]*u0[1] + u0[2]*u0[2]);
        if (n0 > 0.0) { u0[0]/=n0; u0[1]/=n0; u0[2]/=n0; }
        else { u0[0]=1; u0[1]=0; u0[2]=0; }
        #pragma unroll
        for (int i = 0; i < 3; i++)
            u1[i] = H[i][0]*v1[0] + H[i][1]*v1[1] + H[i][2]*v1[2];
        double dp = u0[0]*u1[0] + u0[1]*u1[1] + u0[2]*u1[2];
        u1[0] -= dp*u0[0]; u1[1] -= dp*u0[1]; u1[2] -= dp*u0[2];
        double n1 = sqrt(u1[0]*u1[0] + u1[1]*u1[1] + u1[2]*u1[2]);
        if (n1 > 1e-12 * n0) { u1[0]/=n1; u1[1]/=n1; u1[2]/=n1; }
        else {
            double tv[3] = { (fabs(u0[0]) < 0.9) ? 1.0 : 0.0,
                             (fabs(u0[0]) < 0.9) ? 0.0 : 1.0, 0.0 };
            cross3d(u0, tv, u1);
            double nn = sqrt(u1[0]*u1[0] + u1[1]*u1[1] + u1[2]*u1[2]);
            u1[0]/=nn; u1[1]/=nn; u1[2]/=nn;
        }
        cross3d(u0, u1, u2);                    // det(U) = +1
        double c12[3]; cross3d(v1, v2, c12);
        double detV = v0[0]*c12[0] + v0[1]*c12[1] + v0[2]*c12[2];
        double dsg = (detV >= 0.0) ? 1.0 : -1.0;
        #pragma unroll
        for (int r = 0; r < 3; r++)
            #pragma unroll
            for (int c = 0; c < 3; c++)
                Rg[r][c] = v0[r]*u0[c] + v1[r]*u1[c] + dsg*v2[r]*u2[c];
    }
    double cP[3] = { sP[0]*inv_n, sP[1]*inv_n, sP[2]*inv_n };
    double cQ[3] = { sQ[0]*inv_n, sQ[1]*inv_n, sQ[2]*inv_n };
    #pragma unroll
    for (int i = 0; i < 3; i++) {
        rt[3*i+0] = (float)Rg[i][0];
        rt[3*i+1] = (float)Rg[i][1];
        rt[3*i+2] = (float)Rg[i][2];
        rt[9+i] = (float)(cQ[i] - (Rg[i][0]*cP[0] + Rg[i][1]*cP[1] + Rg[i][2]*cP[2]));
    }
}

// ---------------------------------------------------------------------------
// svd_k: ONE THREAD per domain (64 SIMT-parallel SVDs per wave; 157 waves
// across 256 CUs -> wall time ~ one SVD chain latency). Deliberately NOT
// fused into reduce_k: that would serialize 10,000 one-lane SVD chains'
// instruction issue instead of 157 SIMT waves.
// ---------------------------------------------------------------------------
__global__ __launch_bounds__(128) void svd_k(const float* __restrict__ sums,
                                             float* __restrict__ rt)
{
    int d = blockIdx.x * 128 + threadIdx.x;
    if (d >= N_DOMAIN) return;
    kabsch_from_sums(sums + (size_t)d * 15, rt + (size_t)d * 12);
}

// ---------------------------------------------------------------------------
// apply_low_k: out[n] = Rg[d] * (Mf[g] * pos[n]) + t[d] for n < N_TWIST.
// Reads Mf (out-high scratch) — must precede apply_high_k (kept as two
// dispatches: fusing would race apply_high's writes with Mf reads).
// ---------------------------------------------------------------------------
__global__ void apply_low_k(const float* __restrict__ pos,
                            const float* __restrict__ Mf,
                            const float* __restrict__ rt,
                            float* __restrict__ out)
{
    int n = blockIdx.x * 256 + threadIdx.x;
    if (n >= N_TWIST) return;
    const float* m = Mf + 12 * (n / K_TWIST);
    const float* w = rt + 12 * (n / N_PER_DOM);
    float q0 = pos[3*n+0], q1 = pos[3*n+1], q2 = pos[3*n+2];
    float p0 = m[0]*q0 + m[1]*q1 + m[2]*q2 + m[9];
    float p1 = m[3]*q0 + m[4]*q1 + m[5]*q2 + m[10];
    float p2 = m[6]*q0 + m[7]*q1 + m[8]*q2 + m[11];
    out[3*n+0] = w[0]*p0 + w[1]*p1 + w[2]*p2 + w[9];
    out[3*n+1] = w[3]*p0 + w[4]*p1 + w[5]*p2 + w[10];
    out[3*n+2] = w[6]*p0 + w[7]*p1 + w[8]*p2 + w[11];
}

// ---------------------------------------------------------------------------
// apply_high_k: out[n] = Rg[d] * pos[n] + t[d] for n >= N_TWIST. Overwrites
// the out-high scratch (M0/M1/sums/ctr) — all consumed by now. rt lives in ws.
// ---------------------------------------------------------------------------
__global__ void apply_high_k(const float* __restrict__ pos,
                             const float* __restrict__ rt,
                             float* __restrict__ out)
{
    int i = blockIdx.x * 256 + threadIdx.x;
    int n = N_TWIST + i;
    if (n >= N_NODE) return;
    const float* w = rt + 12 * (n / N_PER_DOM);
    float q0 = pos[3*n+0], q1 = pos[3*n+1], q2 = pos[3*n+2];
    out[3*n+0] = w[0]*q0 + w[1]*q1 + w[2]*q2 + w[9];
    out[3*n+1] = w[3]*q0 + w[4]*q1 + w[5]*q2 + w[10];
    out[3*n+2] = w[6]*q0 + w[7]*q1 + w[8]*q2 + w[11];
}

// ---------------------------------------------------------------------------
extern "C" void kernel_launch(void* const* d_in, const int* in_sizes, int n_in,
                              void* d_out, int out_size, void* d_ws, size_t ws_size,
                              hipStream_t stream)
{
    const float* pos        = (const float*)d_in[0];
    const float* info_level = (const float*)d_in[1];
    const int*   anno       = (const int*)  d_in[2];
    const float* eps        = (const float*)d_in[6];
    const float* uni        = (const float*)d_in[7];
    const int*   from_prior = (const int*)  d_in[8];
    float* out = (float*)d_out;
    float* rt  = (float*)d_ws;                        // 480,000 B (proven safe)

    // scratch in out-high (floats [1.5M, 3M))
    float* M0   = out + (size_t)3 * N_TWIST;          // 150,000 floats
    float* M1   = M0 + 12 * N_GROUP;                  // 150,000 floats
    float* sums = M1 + 12 * N_GROUP;                  // 150,000 floats
    unsigned int* ctr = (unsigned int*)(sums + 15 * N_DOMAIN);  // 8 uints

    // Phase T: ONE fused compose kernel (7 internal device-scope barriers,
    // RELAXED spin + single post-spin fence). Ping-pong M0/M1; o=7 -> M1.
    hipMemsetAsync(ctr, 0, 8 * sizeof(unsigned int), stream);
    compose_all_k<<<CGRID, CBLK, 0, stream>>>(
        pos, info_level, anno, eps, uni, from_prior, M0, M1, ctr);
    float* Mf = M1;

    // Phase R/S: reduce (wave/domain) then thread-per-domain SVD.
    reduce_k<<<N_DOMAIN / 4, 256, 0, stream>>>(pos, Mf, sums);
    svd_k<<<(N_DOMAIN + 127)/128, 128, 0, stream>>>(sums, rt);

    // Phase A: low nodes (reads Mf) then high nodes (overwrites scratch).
    apply_low_k<<<(N_TWIST + 255)/256, 256, 0, stream>>>(pos, Mf, rt, out);
    apply_high_k<<<(N_NODE - N_TWIST + 255)/256, 256, 0, stream>>>(pos, rt, out);
}

// Round 4
// 156.506 us; speedup vs baseline: 1.2196x; 1.2196x over previous
//
#include <hip/hip_runtime.h>
#include <math.h>

#define N_NODE    1000000
#define N_BOND    100000
#define K_TWIST   40
#define MAX_ORDER 8
#define N_DOMAIN  10000
#define N_PER_DOM 100           // N_NODE / N_DOMAIN
#define N_GROUP   12500         // N_BOND / MAX_ORDER
#define N_TWIST   500000        // N_GROUP * K_TWIST  (nodes >= N_TWIST never twisted)
#define SIGMA_MAXF 3.14159265358979323846f

// Session lessons:
//  R5/R6: in-kernel device-wide barriers cost ~7 us/phase on MI355X regardless
//    of poll semantics (cross-XCD L2 writeback/invalidate round trips), while
//    stream dispatch boundaries are ~2 us. 8 compose dispatches win.
//  R7 (this round): NEVER assume ws_size. R3 assumed 256 MiB from poison-fill
//    sizes and may have OOB'd if ws is actually small (only 480 KB was proven
//    in the prior session). Now branched at runtime on the ws_size argument:
//      Path A (ws >= 7.2 MB): prep hoist + slim composes, scratch in ws,
//                             ONE fused apply (no out aliasing).
//      Path B (small ws):     the proven R0 structure (164 us), scratch in
//                             out-high, split apply_low/apply_high.

// ws float layout (Path A):
//   rt    [0,       120000)   10000*12
//   M0    [120000,  270000)   12500*12
//   M1    [270000,  420000)   12500*12
//   sums  [420000,  570000)   10000*15
//   prep  [570000, 1770000)   100000*12, order-major: slot (o*N_GROUP+g)*12
#define WS_RT    0
#define WS_M0    120000
#define WS_M1    270000
#define WS_SUMS  420000
#define WS_PREP  570000
#define WS_FLOATS_NEEDED 1770000u

// ===========================================================================
// Path A kernels
// ===========================================================================

// prep_k: one thread per bond. Hoists everything order-invariant out of the
// compose chain at HIGH parallelism (1563 waves vs the chain's 196):
// trig, anno decode, raw endpoint gathers, endpoint-group indices.
// Stored order-major so compose dispatch o reads 48 B/group fully coalesced.
//   [0]=c [1]=s [2..4]=pos[u] [5..7]=pos[v] [8]=gu [9]=gv [10]=ok [11]=pad
__global__ __launch_bounds__(256) void prep_k(
    const float* __restrict__ pos, const float* __restrict__ info_level,
    const int* __restrict__ anno, const float* __restrict__ eps,
    const float* __restrict__ uni, const int* __restrict__ from_prior_p,
    float* __restrict__ prep)
{
    int b = blockIdx.x * 256 + threadIdx.x;
    if (b >= N_BOND) return;
    int ord = anno[3*b];
    int u   = anno[3*b + 1];
    int v   = anno[3*b + 2];
    float info = info_level[b];
    float ang  = eps[b] * (1.0f - info) * SIGMA_MAXF;
    if (from_prior_p[0] != 0 && info == 0.0f) ang = uni[b];
    int o = b % MAX_ORDER;          // slot read by compose dispatch o
    int g = b / MAX_ORDER;
    float* pr = prep + (size_t)(o * N_GROUP + g) * 12;
    pr[0] = cosf(ang);
    pr[1] = sinf(ang);
    pr[2] = pos[3*u+0]; pr[3] = pos[3*u+1]; pr[4] = pos[3*u+2];
    pr[5] = pos[3*v+0]; pr[6] = pos[3*v+1]; pr[7] = pos[3*v+2];
    int gu = (u < N_TWIST) ? (u / K_TWIST) : -1;
    int gv = (v < N_TWIST) ? (v / K_TWIST) : -1;
    ((int*)pr)[8]  = gu;
    ((int*)pr)[9]  = gv;
    ((int*)pr)[10] = (ord == o) ? 1 : 0;
    pr[11] = 0.f;
}

// compose_k: one thread per group, one dispatch per order (dispatch boundary
// IS the device-wide barrier). Coalesced 48 B prep read -> Mp gathers ->
// ~60 VALU -> 48 B store. Math identical to the verified version.
__global__ __launch_bounds__(256) void compose_k(
    const float* __restrict__ prep,
    const float* __restrict__ Mp, float* __restrict__ Mc, int o)
{
    int g = blockIdx.x * 256 + threadIdx.x;
    if (g >= N_GROUP) return;
    const float4* pr4 = (const float4*)(prep + (size_t)(o * N_GROUP + g) * 12);
    float4 f0 = pr4[0], f1 = pr4[1], f2 = pr4[2];
    float c = f0.x, s = f0.y;
    float pu0 = f0.z, pu1 = f0.w, pu2 = f1.x;
    float pv0 = f1.y, pv1 = f1.z, pv2 = f1.w;
    int gu = __float_as_int(f2.x);
    int gv = __float_as_int(f2.y);
    int ok = __float_as_int(f2.z);
    float* mg = Mc + 12 * g;
    if (!ok) {                                   // safety fallback
        if (o == 0) {
            mg[0]=1.f; mg[1]=0.f; mg[2]=0.f;
            mg[3]=0.f; mg[4]=1.f; mg[5]=0.f;
            mg[6]=0.f; mg[7]=0.f; mg[8]=1.f;
            mg[9]=0.f; mg[10]=0.f; mg[11]=0.f;
        } else {
            const float* mp = Mp + 12 * g;
            #pragma unroll
            for (int k = 0; k < 12; k++) mg[k] = mp[k];
        }
        return;
    }
    if (o > 0) {
        if (gu >= 0) {
            const float* m = Mp + 12 * gu;
            float a = m[0]*pu0 + m[1]*pu1 + m[2]*pu2 + m[9];
            float b = m[3]*pu0 + m[4]*pu1 + m[5]*pu2 + m[10];
            float e = m[6]*pu0 + m[7]*pu1 + m[8]*pu2 + m[11];
            pu0 = a; pu1 = b; pu2 = e;
        }
        if (gv >= 0) {
            const float* m = Mp + 12 * gv;
            float a = m[0]*pv0 + m[1]*pv1 + m[2]*pv2 + m[9];
            float b = m[3]*pv0 + m[4]*pv1 + m[5]*pv2 + m[10];
            float e = m[6]*pv0 + m[7]*pv1 + m[8]*pv2 + m[11];
            pv0 = a; pv1 = b; pv2 = e;
        }
    }
    float ax = pv0-pu0, ay = pv1-pu1, az = pv2-pu2;
    float inv = 1.0f / (sqrtf(ax*ax + ay*ay + az*az) + 1e-12f);
    ax *= inv; ay *= inv; az *= inv;
    float t = 1.0f - c;
    float R00 = c + t*ax*ax,     R01 = -s*az + t*ax*ay, R02 =  s*ay + t*ax*az;
    float R10 =  s*az + t*ay*ax, R11 = c + t*ay*ay,     R12 = -s*ax + t*ay*az;
    float R20 = -s*ay + t*az*ax, R21 =  s*ax + t*az*ay, R22 = c + t*az*az;
    if (o == 0) {
        mg[0]=R00; mg[1]=R01; mg[2]=R02;
        mg[3]=R10; mg[4]=R11; mg[5]=R12;
        mg[6]=R20; mg[7]=R21; mg[8]=R22;
        mg[9]  = pv0 - (R00*pv0 + R01*pv1 + R02*pv2);
        mg[10] = pv1 - (R10*pv0 + R11*pv1 + R12*pv2);
        mg[11] = pv2 - (R20*pv0 + R21*pv1 + R22*pv2);
    } else {
        const float* mp = Mp + 12 * g;
        mg[0] = R00*mp[0] + R01*mp[3] + R02*mp[6];
        mg[1] = R00*mp[1] + R01*mp[4] + R02*mp[7];
        mg[2] = R00*mp[2] + R01*mp[5] + R02*mp[8];
        mg[3] = R10*mp[0] + R11*mp[3] + R12*mp[6];
        mg[4] = R10*mp[1] + R11*mp[4] + R12*mp[7];
        mg[5] = R10*mp[2] + R11*mp[5] + R12*mp[8];
        mg[6] = R20*mp[0] + R21*mp[3] + R22*mp[6];
        mg[7] = R20*mp[1] + R21*mp[4] + R22*mp[7];
        mg[8] = R20*mp[2] + R21*mp[5] + R22*mp[8];
        float d0 = mp[9]-pv0, d1 = mp[10]-pv1, d2 = mp[11]-pv2;
        mg[9]  = R00*d0 + R01*d1 + R02*d2 + pv0;
        mg[10] = R10*d0 + R11*d1 + R12*d2 + pv1;
        mg[11] = R20*d0 + R21*d1 + R22*d2 + pv2;
    }
}

// apply_k (Path A only): ONE fused kernel over all nodes (scratch in ws, no
// aliasing with out).
__global__ void apply_k(const float* __restrict__ pos,
                        const float* __restrict__ Mf,
                        const float* __restrict__ rt,
                        float* __restrict__ out)
{
    int n = blockIdx.x * 256 + threadIdx.x;
    if (n >= N_NODE) return;
    const float* w = rt + 12 * (n / N_PER_DOM);
    float q0 = pos[3*n+0], q1 = pos[3*n+1], q2 = pos[3*n+2];
    float p0 = q0, p1 = q1, p2 = q2;
    if (n < N_TWIST) {
        const float* m = Mf + 12 * (n / K_TWIST);
        p0 = m[0]*q0 + m[1]*q1 + m[2]*q2 + m[9];
        p1 = m[3]*q0 + m[4]*q1 + m[5]*q2 + m[10];
        p2 = m[6]*q0 + m[7]*q1 + m[8]*q2 + m[11];
    }
    out[3*n+0] = w[0]*p0 + w[1]*p1 + w[2]*p2 + w[9];
    out[3*n+1] = w[3]*p0 + w[4]*p1 + w[5]*p2 + w[10];
    out[3*n+2] = w[6]*p0 + w[7]*p1 + w[8]*p2 + w[11];
}

// ===========================================================================
// Path B kernels — byte-identical structure to the proven R0 baseline (164us)
// ===========================================================================

__global__ __launch_bounds__(256) void compose_legacy_k(
    const float* __restrict__ pos, const float* __restrict__ info_level,
    const int* __restrict__ anno, const float* __restrict__ eps,
    const float* __restrict__ uni, const int* __restrict__ from_prior_p,
    const float* __restrict__ Mp, float* __restrict__ Mc, int o)
{
    int g = blockIdx.x * 256 + threadIdx.x;
    if (g >= N_GROUP) return;
    int b = g * MAX_ORDER + o;
    float* mg = Mc + 12 * g;
    if (anno[3*b] != o) {                       // safety fallback
        if (o == 0) {
            mg[0]=1.f; mg[1]=0.f; mg[2]=0.f;
            mg[3]=0.f; mg[4]=1.f; mg[5]=0.f;
            mg[6]=0.f; mg[7]=0.f; mg[8]=1.f;
            mg[9]=0.f; mg[10]=0.f; mg[11]=0.f;
        } else {
            const float* mp = Mp + 12 * g;
            #pragma unroll
            for (int k = 0; k < 12; k++) mg[k] = mp[k];
        }
        return;
    }
    int u = anno[3*b + 1];
    int v = anno[3*b + 2];
    float pu0 = pos[3*u+0], pu1 = pos[3*u+1], pu2 = pos[3*u+2];
    float pv0 = pos[3*v+0], pv1 = pos[3*v+1], pv2 = pos[3*v+2];
    if (o > 0) {
        if (u < N_TWIST) {
            const float* m = Mp + 12 * (u / K_TWIST);
            float a = m[0]*pu0 + m[1]*pu1 + m[2]*pu2 + m[9];
            float c = m[3]*pu0 + m[4]*pu1 + m[5]*pu2 + m[10];
            float e = m[6]*pu0 + m[7]*pu1 + m[8]*pu2 + m[11];
            pu0 = a; pu1 = c; pu2 = e;
        }
        if (v < N_TWIST) {
            const float* m = Mp + 12 * (v / K_TWIST);
            float a = m[0]*pv0 + m[1]*pv1 + m[2]*pv2 + m[9];
            float c = m[3]*pv0 + m[4]*pv1 + m[5]*pv2 + m[10];
            float e = m[6]*pv0 + m[7]*pv1 + m[8]*pv2 + m[11];
            pv0 = a; pv1 = c; pv2 = e;
        }
    }
    float info = info_level[b];
    float ang  = eps[b] * (1.0f - info) * SIGMA_MAXF;
    if (from_prior_p[0] != 0 && info == 0.0f) ang = uni[b];
    float ax = pv0-pu0, ay = pv1-pu1, az = pv2-pu2;
    float inv = 1.0f / (sqrtf(ax*ax + ay*ay + az*az) + 1e-12f);
    ax *= inv; ay *= inv; az *= inv;
    float c = cosf(ang), s = sinf(ang), t = 1.0f - c;
    float R00 = c + t*ax*ax,     R01 = -s*az + t*ax*ay, R02 =  s*ay + t*ax*az;
    float R10 =  s*az + t*ay*ax, R11 = c + t*ay*ay,     R12 = -s*ax + t*ay*az;
    float R20 = -s*ay + t*az*ax, R21 =  s*ax + t*az*ay, R22 = c + t*az*az;
    if (o == 0) {
        mg[0]=R00; mg[1]=R01; mg[2]=R02;
        mg[3]=R10; mg[4]=R11; mg[5]=R12;
        mg[6]=R20; mg[7]=R21; mg[8]=R22;
        mg[9]  = pv0 - (R00*pv0 + R01*pv1 + R02*pv2);
        mg[10] = pv1 - (R10*pv0 + R11*pv1 + R12*pv2);
        mg[11] = pv2 - (R20*pv0 + R21*pv1 + R22*pv2);
    } else {
        const float* mp = Mp + 12 * g;
        mg[0] = R00*mp[0] + R01*mp[3] + R02*mp[6];
        mg[1] = R00*mp[1] + R01*mp[4] + R02*mp[7];
        mg[2] = R00*mp[2] + R01*mp[5] + R02*mp[8];
        mg[3] = R10*mp[0] + R11*mp[3] + R12*mp[6];
        mg[4] = R10*mp[1] + R11*mp[4] + R12*mp[7];
        mg[5] = R10*mp[2] + R11*mp[5] + R12*mp[8];
        mg[6] = R20*mp[0] + R21*mp[3] + R22*mp[6];
        mg[7] = R20*mp[1] + R21*mp[4] + R22*mp[7];
        mg[8] = R20*mp[2] + R21*mp[5] + R22*mp[8];
        float d0 = mp[9]-pv0, d1 = mp[10]-pv1, d2 = mp[11]-pv2;
        mg[9]  = R00*d0 + R01*d1 + R02*d2 + pv0;
        mg[10] = R10*d0 + R11*d1 + R12*d2 + pv1;
        mg[11] = R20*d0 + R21*d1 + R22*d2 + pv2;
    }
}

__global__ void apply_low_k(const float* __restrict__ pos,
                            const float* __restrict__ Mf,
                            const float* __restrict__ rt,
                            float* __restrict__ out)
{
    int n = blockIdx.x * 256 + threadIdx.x;
    if (n >= N_TWIST) return;
    const float* m = Mf + 12 * (n / K_TWIST);
    const float* w = rt + 12 * (n / N_PER_DOM);
    float q0 = pos[3*n+0], q1 = pos[3*n+1], q2 = pos[3*n+2];
    float p0 = m[0]*q0 + m[1]*q1 + m[2]*q2 + m[9];
    float p1 = m[3]*q0 + m[4]*q1 + m[5]*q2 + m[10];
    float p2 = m[6]*q0 + m[7]*q1 + m[8]*q2 + m[11];
    out[3*n+0] = w[0]*p0 + w[1]*p1 + w[2]*p2 + w[9];
    out[3*n+1] = w[3]*p0 + w[4]*p1 + w[5]*p2 + w[10];
    out[3*n+2] = w[6]*p0 + w[7]*p1 + w[8]*p2 + w[11];
}

__global__ void apply_high_k(const float* __restrict__ pos,
                             const float* __restrict__ rt,
                             float* __restrict__ out)
{
    int i = blockIdx.x * 256 + threadIdx.x;
    int n = N_TWIST + i;
    if (n >= N_NODE) return;
    const float* w = rt + 12 * (n / N_PER_DOM);
    float q0 = pos[3*n+0], q1 = pos[3*n+1], q2 = pos[3*n+2];
    out[3*n+0] = w[0]*q0 + w[1]*q1 + w[2]*q2 + w[9];
    out[3*n+1] = w[3]*q0 + w[4]*q1 + w[5]*q2 + w[10];
    out[3*n+2] = w[6]*q0 + w[7]*q1 + w[8]*q2 + w[11];
}

// ===========================================================================
// Shared kernels (both paths)
// ===========================================================================

__global__ __launch_bounds__(256) void reduce_k(const float* __restrict__ pos,
                                                const float* __restrict__ Mf,
                                                float* __restrict__ sums)
{
    int wave = threadIdx.x >> 6;
    int lane = threadIdx.x & 63;
    int d = blockIdx.x * 4 + wave;          // grid = 2500 -> d in [0,10000)
    float a[15];
    #pragma unroll
    for (int k = 0; k < 15; k++) a[k] = 0.f;
    for (int i = lane; i < N_PER_DOM; i += 64) {
        int n = d * N_PER_DOM + i;
        float q0 = pos[3*n+0], q1 = pos[3*n+1], q2 = pos[3*n+2];
        float p0 = q0, p1 = q1, p2 = q2;
        if (n < N_TWIST) {
            const float* m = Mf + 12 * (n / K_TWIST);
            p0 = m[0]*q0 + m[1]*q1 + m[2]*q2 + m[9];
            p1 = m[3]*q0 + m[4]*q1 + m[5]*q2 + m[10];
            p2 = m[6]*q0 + m[7]*q1 + m[8]*q2 + m[11];
        }
        a[0]+=p0;    a[1]+=p1;    a[2]+=p2;
        a[3]+=q0;    a[4]+=q1;    a[5]+=q2;
        a[6]+=p0*q0; a[7]+=p0*q1; a[8]+=p0*q2;
        a[9]+=p1*q0; a[10]+=p1*q1;a[11]+=p1*q2;
        a[12]+=p2*q0;a[13]+=p2*q1;a[14]+=p2*q2;
    }
    #pragma unroll
    for (int off = 32; off > 0; off >>= 1)
        #pragma unroll
        for (int k = 0; k < 15; k++) a[k] += __shfl_down(a[k], off);
    if (lane == 0) {
        float* sd = sums + (size_t)d * 15;
        #pragma unroll
        for (int k = 0; k < 15; k++) sd[k] = a[k];
    }
}

__device__ inline void cross3d(const double a[3], const double b[3], double r[3])
{
    r[0] = a[1]*b[2] - a[2]*b[1];
    r[1] = a[2]*b[0] - a[0]*b[2];
    r[2] = a[0]*b[1] - a[1]*b[0];
}

__device__ void kabsch_from_sums(const float* s, float* __restrict__ rt)
{
    const double inv_n = 1.0 / (double)N_PER_DOM;
    double sP[3] = { s[0], s[1], s[2] };
    double sQ[3] = { s[3], s[4], s[5] };
    double H[3][3];
    #pragma unroll
    for (int i = 0; i < 3; i++)
        #pragma unroll
        for (int j = 0; j < 3; j++)
            H[i][j] = (double)s[6 + 3*i + j] - sP[i]*sQ[j]*inv_n;
    double A[3][3];
    #pragma unroll
    for (int i = 0; i < 3; i++)
        #pragma unroll
        for (int j = 0; j < 3; j++)
            A[i][j] = H[0][i]*H[0][j] + H[1][i]*H[1][j] + H[2][i]*H[2][j];
    double V[3][3] = {{1,0,0},{0,1,0},{0,0,1}};
    for (int sweep = 0; sweep < 30; sweep++) {
        double off = A[0][1]*A[0][1] + A[0][2]*A[0][2] + A[1][2]*A[1][2];
        double n2  = A[0][0]*A[0][0] + A[1][1]*A[1][1] + A[2][2]*A[2][2];
        if (off <= 1e-28 * n2) break;
        for (int pp = 0; pp < 3; pp++) {
            int p = (pp == 2) ? 1 : 0;
            int q = (pp == 0) ? 1 : 2;
            double apq = A[p][q];
            if (apq == 0.0) continue;
            double tau = (A[q][q] - A[p][p]) / (2.0 * apq);
            double tj  = (tau >= 0.0 ? 1.0 : -1.0) / (fabs(tau) + sqrt(1.0 + tau*tau));
            double cj  = 1.0 / sqrt(1.0 + tj*tj);
            double sj  = tj * cj;
            int r = 3 - p - q;
            double app = A[p][p], aqq = A[q][q];
            A[p][p] = app - tj*apq;
            A[q][q] = aqq + tj*apq;
            A[p][q] = 0.0; A[q][p] = 0.0;
            double arp = A[r][p], arq = A[r][q];
            A[r][p] = cj*arp - sj*arq; A[p][r] = A[r][p];
            A[r][q] = sj*arp + cj*arq; A[q][r] = A[r][q];
            #pragma unroll
            for (int k = 0; k < 3; k++) {
                double vp = V[k][p], vq = V[k][q];
                V[k][p] = cj*vp - sj*vq;
                V[k][q] = sj*vp + cj*vq;
            }
        }
    }
    double wv[3] = { A[0][0], A[1][1], A[2][2] };
    int i0 = 0, i1 = 1, i2 = 2;
    if (wv[i0] < wv[i1]) { int t = i0; i0 = i1; i1 = t; }
    if (wv[i0] < wv[i2]) { int t = i0; i0 = i2; i2 = t; }
    if (wv[i1] < wv[i2]) { int t = i1; i1 = i2; i2 = t; }
    double v0[3] = { V[0][i0], V[1][i0], V[2][i0] };
    double v1[3] = { V[0][i1], V[1][i1], V[2][i1] };
    double v2[3] = { V[0][i2], V[1][i2], V[2][i2] };
    double s0 = sqrt(fmax(wv[i0], 0.0));
    double Rg[3][3];
    if (s0 < 1e-200) {
        Rg[0][0]=1; Rg[0][1]=0; Rg[0][2]=0;
        Rg[1][0]=0; Rg[1][1]=1; Rg[1][2]=0;
        Rg[2][0]=0; Rg[2][1]=0; Rg[2][2]=1;
    } else {
        double u0[3], u1[3], u2[3];
        #pragma unroll
        for (int i = 0; i < 3; i++)
            u0[i] = H[i][0]*v0[0] + H[i][1]*v0[1] + H[i][2]*v0[2];
        double n0 = sqrt(u0[0]*u0[0] + u0[1]*u0[1] + u0[2]*u0[2]);
        if (n0 > 0.0) { u0[0]/=n0; u0[1]/=n0; u0[2]/=n0; }
        else { u0[0]=1; u0[1]=0; u0[2]=0; }
        #pragma unroll
        for (int i = 0; i < 3; i++)
            u1[i] = H[i][0]*v1[0] + H[i][1]*v1[1] + H[i][2]*v1[2];
        double dp = u0[0]*u1[0] + u0[1]*u1[1] + u0[2]*u1[2];
        u1[0] -= dp*u0[0]; u1[1] -= dp*u0[1]; u1[2] -= dp*u0[2];
        double n1 = sqrt(u1[0]*u1[0] + u1[1]*u1[1] + u1[2]*u1[2]);
        if (n1 > 1e-12 * n0) { u1[0]/=n1; u1[1]/=n1; u1[2]/=n1; }
        else {
            double tv[3] = { (fabs(u0[0]) < 0.9) ? 1.0 : 0.0,
                             (fabs(u0[0]) < 0.9) ? 0.0 : 1.0, 0.0 };
            cross3d(u0, tv, u1);
            double nn = sqrt(u1[0]*u1[0] + u1[1]*u1[1] + u1[2]*u1[2]);
            u1[0]/=nn; u1[1]/=nn; u1[2]/=nn;
        }
        cross3d(u0, u1, u2);                    // det(U) = +1
        double c12[3]; cross3d(v1, v2, c12);
        double detV = v0[0]*c12[0] + v0[1]*c12[1] + v0[2]*c12[2];
        double dsg = (detV >= 0.0) ? 1.0 : -1.0;
        #pragma unroll
        for (int r = 0; r < 3; r++)
            #pragma unroll
            for (int c = 0; c < 3; c++)
                Rg[r][c] = v0[r]*u0[c] + v1[r]*u1[c] + dsg*v2[r]*u2[c];
    }
    double cP[3] = { sP[0]*inv_n, sP[1]*inv_n, sP[2]*inv_n };
    double cQ[3] = { sQ[0]*inv_n, sQ[1]*inv_n, sQ[2]*inv_n };
    #pragma unroll
    for (int i = 0; i < 3; i++) {
        rt[3*i+0] = (float)Rg[i][0];
        rt[3*i+1] = (float)Rg[i][1];
        rt[3*i+2] = (float)Rg[i][2];
        rt[9+i] = (float)(cQ[i] - (Rg[i][0]*cP[0] + Rg[i][1]*cP[1] + Rg[i][2]*cP[2]));
    }
}

__global__ __launch_bounds__(128) void svd_k(const float* __restrict__ sums,
                                             float* __restrict__ rt)
{
    int d = blockIdx.x * 128 + threadIdx.x;
    if (d >= N_DOMAIN) return;
    kabsch_from_sums(sums + (size_t)d * 15, rt + (size_t)d * 12);
}

// ---------------------------------------------------------------------------
extern "C" void kernel_launch(void* const* d_in, const int* in_sizes, int n_in,
                              void* d_out, int out_size, void* d_ws, size_t ws_size,
                              hipStream_t stream)
{
    const float* pos        = (const float*)d_in[0];
    const float* info_level = (const float*)d_in[1];
    const int*   anno       = (const int*)  d_in[2];
    const float* eps        = (const float*)d_in[6];
    const float* uni        = (const float*)d_in[7];
    const int*   from_prior = (const int*)  d_in[8];
    float* out = (float*)d_out;
    float* ws  = (float*)d_ws;

    if (ws_size >= (size_t)WS_FLOATS_NEEDED * sizeof(float)) {
        // ---------------- Path A: all scratch in ws ----------------
        float* rt   = ws + WS_RT;
        float* M0   = ws + WS_M0;
        float* M1   = ws + WS_M1;
        float* sums = ws + WS_SUMS;
        float* prep = ws + WS_PREP;

        prep_k<<<(N_BOND + 255)/256, 256, 0, stream>>>(
            pos, info_level, anno, eps, uni, from_prior, prep);

        for (int o = 0; o < MAX_ORDER; o++) {
            const float* Mp = (o & 1) ? M0 : M1;
            float*       Mc = (o & 1) ? M1 : M0;
            compose_k<<<(N_GROUP + 255)/256, 256, 0, stream>>>(prep, Mp, Mc, o);
        }
        float* Mf = M1;

        reduce_k<<<N_DOMAIN / 4, 256, 0, stream>>>(pos, Mf, sums);
        svd_k<<<(N_DOMAIN + 127)/128, 128, 0, stream>>>(sums, rt);
        apply_k<<<(N_NODE + 255)/256, 256, 0, stream>>>(pos, Mf, rt, out);
    } else {
        // ---------------- Path B: proven R0 layout (scratch in out-high) ---
        float* rt   = ws;                                 // 480 KB proven safe
        float* M0   = out + (size_t)3 * N_TWIST;          // 150,000 floats
        float* M1   = M0 + 12 * N_GROUP;                  // 150,000 floats
        float* sums = M1 + 12 * N_GROUP;                  // 150,000 floats

        for (int o = 0; o < MAX_ORDER; o++) {
            const float* Mp = (o & 1) ? M0 : M1;
            float*       Mc = (o & 1) ? M1 : M0;
            compose_legacy_k<<<(N_GROUP + 255)/256, 256, 0, stream>>>(
                pos, info_level, anno, eps, uni, from_prior, Mp, Mc, o);
        }
        float* Mf = M1;

        reduce_k<<<N_DOMAIN / 4, 256, 0, stream>>>(pos, Mf, sums);
        svd_k<<<(N_DOMAIN + 127)/128, 128, 0, stream>>>(sums, rt);
        apply_low_k<<<(N_TWIST + 255)/256, 256, 0, stream>>>(pos, Mf, rt, out);
        apply_high_k<<<(N_NODE - N_TWIST + 255)/256, 256, 0, stream>>>(pos, rt, out);
    }
}